// Round 4
// baseline (919.474 us; speedup 1.0000x reference)
//
#include <hip/hip_runtime.h>
#include <hip/hip_bf16.h>

// Trilinear interpolation: input [16][128][128][128] fp32, coords [N][3] in [-1,1],
// out [16][N] fp32.
//
// R4 = R3 with the swizzle-bijection fix: interp_sorted is launched with exactly
// 8*K blocks so l=(b&7)*K+(b>>3) covers [0,8K) bijectively (R3 dropped 4 blocks
// -> 1024 poisoned points -> absmax 2.31).
//
// Pipeline:
//   transpose_bf16 : input -> ws A, bf16 channel-last [128^3][16] (67 MB)
//   zero/count/scan/scatter : bin points into 512 16^3 tiles; B[pos]={cx,cy,cz}, inv[n]=pos
//   interp_sorted  : gather 8 corners x 32 B from A in tile order (L2-local), C[pos] bf16x16
//   unscramble     : out[c*N+n] = C[inv[n]][c]

#define GD   128
#define NCH  16
#define NTILE 8          // 128 cells / 16 per tile
#define NBINS 512        // 8^3 tiles
constexpr int VOX = GD * GD * GD;

__device__ __forceinline__ unsigned short f2bf_rne(float f) {
    unsigned u = __builtin_bit_cast(unsigned, f);
    u = u + 0x7fffu + ((u >> 16) & 1u);   // round-nearest-even
    return (unsigned short)(u >> 16);
}

// ---------- transpose+quantize: [c][s] fp32 -> [s][c] bf16, 4 voxels/thread ----------
__global__ __launch_bounds__(256) void transpose_bf16_k(const float* __restrict__ in,
                                                        unsigned short* __restrict__ ws) {
    int t = blockIdx.x * 256 + threadIdx.x;   // grid sized exactly: VOX/4 threads
    int s = t * 4;
    float4 v[NCH];
#pragma unroll
    for (int c = 0; c < NCH; ++c)
        v[c] = *(const float4*)(in + (size_t)c * VOX + s);

    const float* vf = (const float*)v;        // vf[c*4 + j]
#pragma unroll
    for (int j = 0; j < 4; ++j) {
        unsigned p[8];
#pragma unroll
        for (int k = 0; k < 8; ++k) {
            unsigned lo = f2bf_rne(vf[(2 * k + 0) * 4 + j]);
            unsigned hi = f2bf_rne(vf[(2 * k + 1) * 4 + j]);
            p[k] = lo | (hi << 16);
        }
        uint4* o = (uint4*)(ws + (size_t)(s + j) * NCH);
        o[0] = make_uint4(p[0], p[1], p[2], p[3]);
        o[1] = make_uint4(p[4], p[5], p[6], p[7]);
    }
}

// ---------- binning helpers ----------
__device__ __forceinline__ void grid_coords(const float* __restrict__ coords, int n,
                                            float& cx, float& cy, float& cz) {
    cx = (coords[3 * n + 0] + 1.0f) * 0.5f * (float)(GD - 1);
    cy = (coords[3 * n + 1] + 1.0f) * 0.5f * (float)(GD - 1);
    cz = (coords[3 * n + 2] + 1.0f) * 0.5f * (float)(GD - 1);
}

__device__ __forceinline__ int tile_of(float cx, float cy, float cz) {
    int ix = min(max((int)floorf(cx), 0), GD - 1);
    int iy = min(max((int)floorf(cy), 0), GD - 1);
    int iz = min(max((int)floorf(cz), 0), GD - 1);
    return ((ix >> 4) * NTILE + (iy >> 4)) * NTILE + (iz >> 4);
}

__global__ void zero_bins_k(unsigned* __restrict__ bins) {
    bins[threadIdx.x] = 0u;   // 1 block x NBINS threads
}

__global__ __launch_bounds__(256) void count_k(const float* __restrict__ coords,
                                               unsigned* __restrict__ bins, int N) {
    int n = blockIdx.x * 256 + threadIdx.x;
    if (n >= N) return;
    float cx, cy, cz; grid_coords(coords, n, cx, cy, cz);
    atomicAdd(&bins[tile_of(cx, cy, cz)], 1u);
}

__global__ void scan_k(const unsigned* __restrict__ bins, unsigned* __restrict__ offs) {
    __shared__ unsigned s[NBINS];
    int t = threadIdx.x;                       // 1 block x NBINS threads
    s[t] = bins[t];
    __syncthreads();
    unsigned orig = s[t];
    for (int d = 1; d < NBINS; d <<= 1) {
        unsigned add = (t >= d) ? s[t - d] : 0u;
        __syncthreads();
        s[t] += add;
        __syncthreads();
    }
    offs[t] = s[t] - orig;                     // exclusive prefix
}

__global__ __launch_bounds__(256) void scatter_k(const float* __restrict__ coords,
                                                 unsigned* __restrict__ offs,
                                                 float4* __restrict__ B,
                                                 unsigned* __restrict__ inv, int N) {
    int n = blockIdx.x * 256 + threadIdx.x;
    if (n >= N) return;
    float cx, cy, cz; grid_coords(coords, n, cx, cy, cz);
    unsigned pos = atomicAdd(&offs[tile_of(cx, cy, cz)], 1u);
    B[pos] = make_float4(cx, cy, cz, 0.0f);
    inv[n] = pos;
}

// ---------- interp in sorted order: gathers are L2-local ----------
__global__ __launch_bounds__(256) void interp_sorted_k(const unsigned short* __restrict__ ws,
                                                       const float4* __restrict__ B,
                                                       unsigned short* __restrict__ C,
                                                       int N, int K) {
    // Grid is exactly 8*K blocks, so l = (b&7)*K + (b>>3) is a bijection onto
    // [0, 8K): each XCD (b%8 round-robin) gets a contiguous run of K logical
    // blocks -> its tile regions stay resident in its 4 MB L2.
    int l = (blockIdx.x & 7) * K + (blockIdx.x >> 3);
    int i = l * 256 + threadIdx.x;
    if (i >= N) return;

    float4 r = B[i];
    float cx = r.x, cy = r.y, cz = r.z;

    float fx = floorf(cx), fy = floorf(cy), fz = floorf(cz);
    float tx = cx - fx, ty = cy - fy, tz = cz - fz;
    int ix = (int)fx, iy = (int)fy, iz = (int)fz;

    int ix0 = min(max(ix,     0), GD - 1), ix1 = min(max(ix + 1, 0), GD - 1);
    int iy0 = min(max(iy,     0), GD - 1), iy1 = min(max(iy + 1, 0), GD - 1);
    int iz0 = min(max(iz,     0), GD - 1), iz1 = min(max(iz + 1, 0), GD - 1);

    float wx0 = 1.0f - tx, wx1 = tx;
    float wy0 = 1.0f - ty, wy1 = ty;
    float wz0 = 1.0f - tz, wz1 = tz;

    size_t bx0 = (size_t)ix0 * (GD * GD * NCH), bx1 = (size_t)ix1 * (GD * GD * NCH);
    size_t by0 = (size_t)iy0 * (GD * NCH),      by1 = (size_t)iy1 * (GD * NCH);
    size_t bz0 = (size_t)iz0 * NCH,             bz1 = (size_t)iz1 * NCH;

    float acc[NCH];
#pragma unroll
    for (int c = 0; c < NCH; ++c) acc[c] = 0.0f;

#define CORNER(BX, BY, BZ, W)                                                  \
    {                                                                          \
        const uint4* p = (const uint4*)(ws + (BX) + (BY) + (BZ));              \
        uint4 A0 = p[0], A1 = p[1];                                            \
        unsigned u[8] = {A0.x, A0.y, A0.z, A0.w, A1.x, A1.y, A1.z, A1.w};      \
        float w = (W);                                                         \
        _Pragma("unroll")                                                      \
        for (int k = 0; k < 8; ++k) {                                          \
            float lo = __builtin_bit_cast(float, u[k] << 16);                  \
            float hi = __builtin_bit_cast(float, u[k] & 0xffff0000u);          \
            acc[2 * k + 0] += w * lo;                                          \
            acc[2 * k + 1] += w * hi;                                          \
        }                                                                      \
    }

    CORNER(bx0, by0, bz0, wx0 * wy0 * wz0)
    CORNER(bx0, by0, bz1, wx0 * wy0 * wz1)
    CORNER(bx0, by1, bz0, wx0 * wy1 * wz0)
    CORNER(bx0, by1, bz1, wx0 * wy1 * wz1)
    CORNER(bx1, by0, bz0, wx1 * wy0 * wz0)
    CORNER(bx1, by0, bz1, wx1 * wy0 * wz1)
    CORNER(bx1, by1, bz0, wx1 * wy1 * wz0)
    CORNER(bx1, by1, bz1, wx1 * wy1 * wz1)
#undef CORNER

    unsigned q[8];
#pragma unroll
    for (int k = 0; k < 8; ++k) {
        unsigned lo = f2bf_rne(acc[2 * k + 0]);
        unsigned hi = f2bf_rne(acc[2 * k + 1]);
        q[k] = lo | (hi << 16);
    }
    uint4* o = (uint4*)(C + (size_t)i * NCH);   // coalesced 32 B/thread
    o[0] = make_uint4(q[0], q[1], q[2], q[3]);
    o[1] = make_uint4(q[4], q[5], q[6], q[7]);
}

// ---------- invert the permutation: out[c][n] = C[inv[n]][c] ----------
__global__ __launch_bounds__(256) void unscramble_k(const unsigned short* __restrict__ C,
                                                    const unsigned* __restrict__ inv,
                                                    float* __restrict__ out, int N) {
    int n = blockIdx.x * 256 + threadIdx.x;
    if (n >= N) return;
    unsigned pos = inv[n];
    const uint4* p = (const uint4*)(C + (size_t)pos * NCH);
    uint4 A0 = p[0], A1 = p[1];
    unsigned u[8] = {A0.x, A0.y, A0.z, A0.w, A1.x, A1.y, A1.z, A1.w};
#pragma unroll
    for (int k = 0; k < 8; ++k) {
        out[(size_t)(2 * k + 0) * N + n] = __builtin_bit_cast(float, u[k] << 16);
        out[(size_t)(2 * k + 1) * N + n] = __builtin_bit_cast(float, u[k] & 0xffff0000u);
    }
}

// ---------- fallback: direct gather from native layout (fp32) ----------
__global__ __launch_bounds__(256) void interp_direct_k(const float* __restrict__ in,
                                                       const float* __restrict__ coords,
                                                       float* __restrict__ out, int N) {
    int n = blockIdx.x * 256 + threadIdx.x;
    if (n >= N) return;
    float cx, cy, cz; grid_coords(coords, n, cx, cy, cz);
    float fx = floorf(cx), fy = floorf(cy), fz = floorf(cz);
    float tx = cx - fx, ty = cy - fy, tz = cz - fz;
    int ix = (int)fx, iy = (int)fy, iz = (int)fz;
    int ix0 = min(max(ix, 0), GD - 1), ix1 = min(max(ix + 1, 0), GD - 1);
    int iy0 = min(max(iy, 0), GD - 1), iy1 = min(max(iy + 1, 0), GD - 1);
    int iz0 = min(max(iz, 0), GD - 1), iz1 = min(max(iz + 1, 0), GD - 1);
    float wx0 = 1.0f - tx, wx1 = tx, wy0 = 1.0f - ty, wy1 = ty, wz0 = 1.0f - tz, wz1 = tz;
    int o000 = (ix0 * GD + iy0) * GD + iz0, o001 = (ix0 * GD + iy0) * GD + iz1;
    int o010 = (ix0 * GD + iy1) * GD + iz0, o011 = (ix0 * GD + iy1) * GD + iz1;
    int o100 = (ix1 * GD + iy0) * GD + iz0, o101 = (ix1 * GD + iy0) * GD + iz1;
    int o110 = (ix1 * GD + iy1) * GD + iz0, o111 = (ix1 * GD + iy1) * GD + iz1;
    float w000 = wx0 * wy0 * wz0, w001 = wx0 * wy0 * wz1;
    float w010 = wx0 * wy1 * wz0, w011 = wx0 * wy1 * wz1;
    float w100 = wx1 * wy0 * wz0, w101 = wx1 * wy0 * wz1;
    float w110 = wx1 * wy1 * wz0, w111 = wx1 * wy1 * wz1;
#pragma unroll
    for (int c = 0; c < NCH; ++c) {
        const float* g = in + (size_t)c * VOX;
        float acc = w000 * g[o000] + w001 * g[o001] + w010 * g[o010] + w011 * g[o011]
                  + w100 * g[o100] + w101 * g[o101] + w110 * g[o110] + w111 * g[o111];
        out[(size_t)c * N + n] = acc;
    }
}

extern "C" void kernel_launch(void* const* d_in, const int* in_sizes, int n_in,
                              void* d_out, int out_size, void* d_ws, size_t ws_size,
                              hipStream_t stream) {
    const float* input  = (const float*)d_in[0];
    const float* coords = (const float*)d_in[1];
    float* out = (float*)d_out;
    int N = in_sizes[1] / 3;  // 1,000,000

    char* w = (char*)d_ws;
    size_t offA    = 0;                                   // bf16 channel-last grid
    size_t offB    = offA + (size_t)VOX * NCH * 2;        // sorted records float4
    size_t offInv  = offB + (size_t)N * 16;               // inv perm (u32)
    size_t offC    = offInv + (size_t)N * 4;              // bf16 results, sorted order
    size_t offBins = offC + (size_t)N * NCH * 2;          // bins + offs
    size_t need    = offBins + 2 * NBINS * 4;

    int nb = (N + 255) / 256;

    if (ws_size >= need) {
        unsigned short* A   = (unsigned short*)(w + offA);
        float4*         B   = (float4*)(w + offB);
        unsigned*       inv = (unsigned*)(w + offInv);
        unsigned short* C   = (unsigned short*)(w + offC);
        unsigned*       bins = (unsigned*)(w + offBins);
        unsigned*       offs = bins + NBINS;
        int K  = (nb + 7) / 8;
        int nb8 = 8 * K;   // bijection: grid must be exactly 8*K blocks

        transpose_bf16_k<<<VOX / 4 / 256, 256, 0, stream>>>(input, A);
        zero_bins_k<<<1, NBINS, 0, stream>>>(bins);
        count_k<<<nb, 256, 0, stream>>>(coords, bins, N);
        scan_k<<<1, NBINS, 0, stream>>>(bins, offs);
        scatter_k<<<nb, 256, 0, stream>>>(coords, offs, B, inv, N);
        interp_sorted_k<<<nb8, 256, 0, stream>>>(A, B, C, N, K);
        unscramble_k<<<nb, 256, 0, stream>>>(C, inv, out, N);
    } else {
        interp_direct_k<<<nb, 256, 0, stream>>>(input, coords, out, N);
    }
}

// Round 5
// 344.005 us; speedup vs baseline: 2.6729x; 2.6729x over previous
//
#include <hip/hip_runtime.h>
#include <hip/hip_bf16.h>

// Trilinear interpolation: input [16][128][128][128] fp32, coords [N][3] in [-1,1],
// out [16][N] fp32.
//
// R5: overlapping z-pair layout. ws P[x][y][z] is one 64 B line holding the 16
// bf16 channels of voxel (x,y,z) AND of (x,y,min(z+1,127)). Each of the 4
// (x,y)-corners of a query then needs exactly ONE aligned 64 B line -> 4 lines
// = 256 B/point, i.e. 100% line utilization (the bf16x16ch payload floor).
// R2 measured 369 MB fetch (E[6 lines/pt]); this removes the z-split waste.
// No sorting: R4 showed 512-bin global atomics cost ~600 us — strictly worse.

#define GD   128
#define NCH  16
constexpr int VOX = GD * GD * GD;

__device__ __forceinline__ unsigned short f2bf_rne(float f) {
    unsigned u = __builtin_bit_cast(unsigned, f);
    u = u + 0x7fffu + ((u >> 16) & 1u);   // round-nearest-even
    return (unsigned short)(u >> 16);
}

// ---------- build pair layout: [c][s] fp32 -> P[s] = {bf16x16 @ z, bf16x16 @ z+1} ----------
__global__ __launch_bounds__(256) void transpose_pair_k(const float* __restrict__ in,
                                                        uint4* __restrict__ ws) {
    int s = blockIdx.x * 256 + threadIdx.x;   // grid sized exactly: VOX threads
    int z = s & (GD - 1);
    int s1 = s + (z < GD - 1 ? 1 : 0);        // clamp at the z edge -> (127,127)

    unsigned pz0[8], pz1[8];
#pragma unroll
    for (int k = 0; k < 8; ++k) {
        // coalesced 4 B reads per channel (two streams, second mostly L1/L2-hit)
        float a0 = in[(size_t)(2 * k + 0) * VOX + s];
        float a1 = in[(size_t)(2 * k + 1) * VOX + s];
        float b0 = in[(size_t)(2 * k + 0) * VOX + s1];
        float b1 = in[(size_t)(2 * k + 1) * VOX + s1];
        pz0[k] = (unsigned)f2bf_rne(a0) | ((unsigned)f2bf_rne(a1) << 16);
        pz1[k] = (unsigned)f2bf_rne(b0) | ((unsigned)f2bf_rne(b1) << 16);
    }
    uint4* o = ws + (size_t)s * 4;            // 64 B/thread contiguous
    o[0] = make_uint4(pz0[0], pz0[1], pz0[2], pz0[3]);
    o[1] = make_uint4(pz0[4], pz0[5], pz0[6], pz0[7]);
    o[2] = make_uint4(pz1[0], pz1[1], pz1[2], pz1[3]);
    o[3] = make_uint4(pz1[4], pz1[5], pz1[6], pz1[7]);
}

// ---------- interp: 4 corner-lines x 64 B, each line has both z voxels ----------
__global__ __launch_bounds__(256) void interp_pair_k(const uint4* __restrict__ ws,
                                                     const float* __restrict__ coords,
                                                     float* __restrict__ out, int N) {
    int n = blockIdx.x * 256 + threadIdx.x;
    if (n >= N) return;

    float cx = (coords[3 * n + 0] + 1.0f) * 0.5f * (float)(GD - 1);
    float cy = (coords[3 * n + 1] + 1.0f) * 0.5f * (float)(GD - 1);
    float cz = (coords[3 * n + 2] + 1.0f) * 0.5f * (float)(GD - 1);

    float fx = floorf(cx), fy = floorf(cy), fz = floorf(cz);
    float tx = cx - fx, ty = cy - fy, tz = cz - fz;
    int ix = (int)fx, iy = (int)fy, iz = (int)fz;

    int ix0 = min(max(ix,     0), GD - 1), ix1 = min(max(ix + 1, 0), GD - 1);
    int iy0 = min(max(iy,     0), GD - 1), iy1 = min(max(iy + 1, 0), GD - 1);
    int iz0 = min(max(iz,     0), GD - 1);
    // pair line at iz0 holds z=iz0 and z=min(iz0+1, GD-1) == clamped iz1. exact.

    float wx0 = 1.0f - tx, wx1 = tx;
    float wy0 = 1.0f - ty, wy1 = ty;
    float wz0 = 1.0f - tz, wz1 = tz;

    size_t b00 = ((size_t)(ix0 * GD + iy0) * GD + iz0) * 4;   // uint4 units
    size_t b01 = ((size_t)(ix0 * GD + iy1) * GD + iz0) * 4;
    size_t b10 = ((size_t)(ix1 * GD + iy0) * GD + iz0) * 4;
    size_t b11 = ((size_t)(ix1 * GD + iy1) * GD + iz0) * 4;

    float acc[NCH];
#pragma unroll
    for (int c = 0; c < NCH; ++c) acc[c] = 0.0f;

#define CORNER(BASE, WXY)                                                      \
    {                                                                          \
        const uint4* p = ws + (BASE);                                          \
        uint4 q0 = p[0], q1 = p[1], q2 = p[2], q3 = p[3];                      \
        unsigned u0[8] = {q0.x, q0.y, q0.z, q0.w, q1.x, q1.y, q1.z, q1.w};     \
        unsigned u1[8] = {q2.x, q2.y, q2.z, q2.w, q3.x, q3.y, q3.z, q3.w};     \
        float wxy = (WXY);                                                     \
        _Pragma("unroll")                                                      \
        for (int k = 0; k < 8; ++k) {                                          \
            float z0lo = __builtin_bit_cast(float, u0[k] << 16);               \
            float z0hi = __builtin_bit_cast(float, u0[k] & 0xffff0000u);       \
            float z1lo = __builtin_bit_cast(float, u1[k] << 16);               \
            float z1hi = __builtin_bit_cast(float, u1[k] & 0xffff0000u);       \
            acc[2 * k + 0] += wxy * (wz0 * z0lo + wz1 * z1lo);                 \
            acc[2 * k + 1] += wxy * (wz0 * z0hi + wz1 * z1hi);                 \
        }                                                                      \
    }

    CORNER(b00, wx0 * wy0)
    CORNER(b01, wx0 * wy1)
    CORNER(b10, wx1 * wy0)
    CORNER(b11, wx1 * wy1)
#undef CORNER

#pragma unroll
    for (int c = 0; c < NCH; ++c)
        out[(size_t)c * N + n] = acc[c];   // coalesced strided stores
}

// ---------- fallback: direct gather from native layout (fp32) ----------
__global__ __launch_bounds__(256) void interp_direct_k(const float* __restrict__ in,
                                                       const float* __restrict__ coords,
                                                       float* __restrict__ out, int N) {
    int n = blockIdx.x * 256 + threadIdx.x;
    if (n >= N) return;
    float cx = (coords[3 * n + 0] + 1.0f) * 0.5f * (float)(GD - 1);
    float cy = (coords[3 * n + 1] + 1.0f) * 0.5f * (float)(GD - 1);
    float cz = (coords[3 * n + 2] + 1.0f) * 0.5f * (float)(GD - 1);
    float fx = floorf(cx), fy = floorf(cy), fz = floorf(cz);
    float tx = cx - fx, ty = cy - fy, tz = cz - fz;
    int ix = (int)fx, iy = (int)fy, iz = (int)fz;
    int ix0 = min(max(ix, 0), GD - 1), ix1 = min(max(ix + 1, 0), GD - 1);
    int iy0 = min(max(iy, 0), GD - 1), iy1 = min(max(iy + 1, 0), GD - 1);
    int iz0 = min(max(iz, 0), GD - 1), iz1 = min(max(iz + 1, 0), GD - 1);
    float wx0 = 1.0f - tx, wx1 = tx, wy0 = 1.0f - ty, wy1 = ty, wz0 = 1.0f - tz, wz1 = tz;
    int o000 = (ix0 * GD + iy0) * GD + iz0, o001 = (ix0 * GD + iy0) * GD + iz1;
    int o010 = (ix0 * GD + iy1) * GD + iz0, o011 = (ix0 * GD + iy1) * GD + iz1;
    int o100 = (ix1 * GD + iy0) * GD + iz0, o101 = (ix1 * GD + iy0) * GD + iz1;
    int o110 = (ix1 * GD + iy1) * GD + iz0, o111 = (ix1 * GD + iy1) * GD + iz1;
    float w000 = wx0 * wy0 * wz0, w001 = wx0 * wy0 * wz1;
    float w010 = wx0 * wy1 * wz0, w011 = wx0 * wy1 * wz1;
    float w100 = wx1 * wy0 * wz0, w101 = wx1 * wy0 * wz1;
    float w110 = wx1 * wy1 * wz0, w111 = wx1 * wy1 * wz1;
#pragma unroll
    for (int c = 0; c < NCH; ++c) {
        const float* g = in + (size_t)c * VOX;
        float acc = w000 * g[o000] + w001 * g[o001] + w010 * g[o010] + w011 * g[o011]
                  + w100 * g[o100] + w101 * g[o101] + w110 * g[o110] + w111 * g[o111];
        out[(size_t)c * N + n] = acc;
    }
}

extern "C" void kernel_launch(void* const* d_in, const int* in_sizes, int n_in,
                              void* d_out, int out_size, void* d_ws, size_t ws_size,
                              hipStream_t stream) {
    const float* input  = (const float*)d_in[0];
    const float* coords = (const float*)d_in[1];
    float* out = (float*)d_out;
    int N = in_sizes[1] / 3;  // 1,000,000
    int nb = (N + 255) / 256;

    size_t need = (size_t)VOX * 64;  // 134,217,728 B pair layout (== R1's ws, known to fit)
    if (ws_size >= need) {
        transpose_pair_k<<<VOX / 256, 256, 0, stream>>>(input, (uint4*)d_ws);
        interp_pair_k<<<nb, 256, 0, stream>>>((const uint4*)d_ws, coords, out, N);
    } else {
        interp_direct_k<<<nb, 256, 0, stream>>>(input, coords, out, N);
    }
}